// Round 6
// baseline (51.286 us; speedup 1.0000x reference)
//
#include <hip/hip_runtime.h>

// GroupWiseAgg: MVS group-wise correlation cost volume.
// features: (NVIEW=4, C=32, H=112, W=144) fp32
// proj:     (NVIEW, 2, 4, 4) fp32  [0]=extrinsic E, [1]=intrinsic K
// depth:    (D=48, H=112, W=144) fp32
// out:      (G=8, D, H, W) fp32
//
// R6: fp16 HWC taps + XCD banding (R5) + HAND-HELD 2-deep depth pipeline:
// tap loads are inline-asm global_load_dwordx4 (invisible to the compiler's
// SIInsertWaitcnts model), synchronized with explicit counted s_waitcnt
// vmcnt(N) + sched_barrier(0). Compiler-visible loads (refq, deps) are
// force-completed BEFORE the first asm load so the compiler never emits a
// draining vmcnt mid-pipeline.
//
// vmcnt FIFO ledger (per thread, in issue order):
//   PREP0 x12, PREP1 x12                     | wait vmcnt(12) -> PREP0 done
//   CONS0 stores x2, PREP2 x12               | wait vmcnt(14) -> PREP1 done
//   CONS1 stores x2, PREP3 x12               | wait vmcnt(14) -> PREP2 done
//   CONS2 stores x2                          | wait vmcnt(2)  -> PREP3 done
//   CONS3 stores x2

typedef _Float16 h2  __attribute__((ext_vector_type(2)));
typedef _Float16 h8v __attribute__((ext_vector_type(8)));

constexpr int NVIEW = 4;
constexpr int C     = 32;
constexpr int D     = 48;
constexpr int H     = 112;
constexpr int W     = 144;
constexpr int HW    = H * W;        // 16128
constexpr int TOTAL = D * HW;       // 774144
constexpr int DCHUNK = 4;
constexpr int NDC    = D / DCHUNK;  // 12
constexpr int NXCD   = 8;
constexpr int BAND   = HW / NXCD;   // 2016 pixels
constexpr int WPB    = 64;          // wids per block
constexpr int BLK_PER_XCD = (BAND * NDC) / WPB;  // 378

#if __has_builtin(__builtin_amdgcn_fdot2)
__device__ inline float dot2f(h2 a, h2 b, float c) {
    return __builtin_amdgcn_fdot2(a, b, c, false);
}
#else
__device__ inline float dot2f(h2 a, h2 b, float c) {
    return fmaf((float)a.x, (float)b.x, fmaf((float)a.y, (float)b.y, c));
}
#endif

__device__ inline h2 as_h2(float f) { union { float f; h2 h; } u; u.f = f; return u.h; }

// raw 16B global load, NOT tracked by the compiler's waitcnt model
__device__ inline float4 gload16(const void* addr) {
    float4 d;
    asm volatile("global_load_dwordx4 %0, %1, off"
                 : "=v"(d) : "v"(addr) : "memory");
    return d;
}

#define WAITCNT(N) { asm volatile("s_waitcnt vmcnt(" #N ")" ::: "memory"); \
                     __builtin_amdgcn_sched_barrier(0); }

// ---------- matrix helpers (thread-0 only) ----------
__device__ inline void fold_mat(const float* pm, double out[16]) {
    const float* E = pm;
    const float* K = pm + 16;
    for (int i = 0; i < 3; ++i)
        for (int j = 0; j < 4; ++j) {
            double s = 0.0;
            for (int k = 0; k < 3; ++k) s += (double)K[i*4+k] * (double)E[k*4+j];
            out[i*4+j] = s;
        }
    for (int j = 0; j < 4; ++j) out[12+j] = (double)E[12+j];
}

__device__ inline void inv4(const double A[16], double out[16]) {
    double M[4][8];
    for (int r = 0; r < 4; ++r) {
        for (int c = 0; c < 4; ++c) M[r][c] = A[r*4+c];
        for (int c = 0; c < 4; ++c) M[r][4+c] = (r == c) ? 1.0 : 0.0;
    }
    for (int col = 0; col < 4; ++col) {
        int piv = col;
        double best = fabs(M[col][col]);
        for (int r = col+1; r < 4; ++r) {
            double v = fabs(M[r][col]);
            if (v > best) { best = v; piv = r; }
        }
        if (piv != col)
            for (int c = 0; c < 8; ++c) { double t = M[col][c]; M[col][c] = M[piv][c]; M[piv][c] = t; }
        double ip = 1.0 / M[col][col];
        for (int c = 0; c < 8; ++c) M[col][c] *= ip;
        for (int r = 0; r < 4; ++r) {
            if (r == col) continue;
            double f = M[r][col];
            if (f != 0.0)
                for (int c = 0; c < 8; ++c) M[r][c] -= f * M[col][c];
        }
    }
    for (int r = 0; r < 4; ++r)
        for (int c = 0; c < 4; ++c) out[r*4+c] = M[r][4+c];
}

__device__ inline void compute_rt(const float* proj, float* dst) {
    double Pref[16], Pinv[16];
    fold_mat(proj, Pref);
    inv4(Pref, Pinv);
    for (int v = 1; v < NVIEW; ++v) {
        double Ps[16], Pr[16];
        fold_mat(proj + v*32, Ps);
        for (int i = 0; i < 4; ++i)
            for (int j = 0; j < 4; ++j) {
                double s = 0.0;
                for (int k = 0; k < 4; ++k) s += Ps[i*4+k] * Pinv[k*4+j];
                Pr[i*4+j] = s;
            }
        float* o = dst + (v-1)*12;
        for (int i = 0; i < 3; ++i)
            for (int j = 0; j < 3; ++j) o[i*3+j] = (float)Pr[i*4+j];
        for (int i = 0; i < 3; ++i) o[9+i] = (float)Pr[i*4+3];
    }
}

// ---------- transpose CHW fp32 -> HWC fp16 ----------
__global__ __launch_bounds__(256) void transpose_h(
    const float* __restrict__ fea, _Float16* __restrict__ feaH)
{
    const int t = blockIdx.x * blockDim.x + threadIdx.x;  // v*HW + p
    const int v = t / HW;
    const int p = t - v * HW;
    const float* src = fea + (size_t)v*C*HW + p;
    h8v ov[4];
    #pragma unroll
    for (int q = 0; q < 4; ++q) {
        #pragma unroll
        for (int k = 0; k < 8; ++k) ov[q][k] = (_Float16)src[(q*8+k)*HW];
    }
    h8v* dst = (h8v*)(feaH + (size_t)t * C);
    #pragma unroll
    for (int q = 0; q < 4; ++q) dst[q] = ov[q];
}

// ---------- main kernel ----------
// PREP: compute weights into wgt[BUF], issue 12 asm loads into ftaps[BUF]
#define PREP(DD, BUF) { \
    const float dep_ = deps[DD]; \
    _Pragma("unroll") \
    for (int v_ = 0; v_ < 3; ++v_) { \
        const float X_ = fmaf(rx[v_], dep_, tx[v_]); \
        const float Y_ = fmaf(ry[v_], dep_, ty[v_]); \
        const float Z_ = fmaf(rz[v_], dep_, tz[v_]); \
        const float iZ_ = __builtin_amdgcn_rcpf(Z_); \
        const float px_ = X_ * iZ_, py_ = Y_ * iZ_; \
        const float x0f_ = floorf(px_), y0f_ = floorf(py_); \
        const float dx_ = px_ - x0f_, dy_ = py_ - y0f_; \
        const int x0_ = (int)x0f_, y0_ = (int)y0f_; \
        const int x1_ = x0_ + 1,  y1_ = y0_ + 1; \
        float w00_ = (1.f-dx_)*(1.f-dy_); \
        float w10_ = dx_*(1.f-dy_); \
        float w01_ = (1.f-dx_)*dy_; \
        float w11_ = dx_*dy_; \
        const bool vx0_ = (x0_ >= 0) & (x0_ < W); \
        const bool vx1_ = (x1_ >= 0) & (x1_ < W); \
        const bool vy0_ = (y0_ >= 0) & (y0_ < H); \
        const bool vy1_ = (y1_ >= 0) & (y1_ < H); \
        if (!(vx0_ && vy0_)) w00_ = 0.f; \
        if (!(vx1_ && vy0_)) w10_ = 0.f; \
        if (!(vx0_ && vy1_)) w01_ = 0.f; \
        if (!(vx1_ && vy1_)) w11_ = 0.f; \
        const int xc0_ = min(max(x0_,0),W-1), xc1_ = min(max(x1_,0),W-1); \
        const int yc0_ = min(max(y0_,0),H-1), yc1_ = min(max(y1_,0),H-1); \
        const int off_[4] = { yc0_*W+xc0_, yc0_*W+xc1_, yc1_*W+xc0_, yc1_*W+xc1_ }; \
        const float wf_[4] = { w00_, w10_, w01_, w11_ }; \
        const _Float16* base_ = feaH + (size_t)(v_+1)*HW*C + l*8; \
        _Pragma("unroll") \
        for (int t_ = 0; t_ < 4; ++t_) { \
            ftaps[BUF][v_][t_] = gload16(base_ + (size_t)off_[t_]*C); \
            const _Float16 wh_ = (_Float16)wf_[t_]; \
            h2 wt_; wt_.x = wh_; wt_.y = wh_; \
            wgt[BUF][v_][t_] = wt_; \
        } \
    } \
}

// CONS: consume ftaps[BUF]/wgt[BUF] (caller guarantees data has landed)
#define CONS(DD, BUF) { \
    float accA_ = 0.f, accB_ = 0.f; \
    _Pragma("unroll") \
    for (int v_ = 0; v_ < 3; ++v_) { \
        h2 s0_, s1_, s2_, s3_; \
        { const float4 t_ = ftaps[BUF][v_][0]; const h2 w_ = wgt[BUF][v_][0]; \
          s0_ = w_ * as_h2(t_.x); s1_ = w_ * as_h2(t_.y); \
          s2_ = w_ * as_h2(t_.z); s3_ = w_ * as_h2(t_.w); } \
        _Pragma("unroll") \
        for (int k_ = 1; k_ < 4; ++k_) { \
            const float4 t_ = ftaps[BUF][v_][k_]; const h2 w_ = wgt[BUF][v_][k_]; \
            s0_ += w_ * as_h2(t_.x); s1_ += w_ * as_h2(t_.y); \
            s2_ += w_ * as_h2(t_.z); s3_ += w_ * as_h2(t_.w); \
        } \
        accA_ = dot2f(s0_, refq[0], accA_); \
        accA_ = dot2f(s1_, refq[1], accA_); \
        accB_ = dot2f(s2_, refq[2], accB_); \
        accB_ = dot2f(s3_, refq[3], accB_); \
    } \
    const int didx_ = (dc*DCHUNK + (DD))*HW + p; \
    __builtin_nontemporal_store(accA_ * scale, &out[(2*l  )*TOTAL + didx_]); \
    __builtin_nontemporal_store(accB_ * scale, &out[(2*l+1)*TOTAL + didx_]); \
}

__global__ __launch_bounds__(256) void gwc_main(
    const _Float16* __restrict__ feaH,  // (NVIEW, HW, C) fp16
    const float* __restrict__ proj,     // (NVIEW, 2, 4, 4)
    const float* __restrict__ depth,    // (D, HW)
    float* __restrict__ out)            // (G=8, D, HW)
{
    __shared__ float s_rt[(NVIEW-1)*12];
    if (threadIdx.x == 0) compute_rt(proj, s_rt);
    __syncthreads();

    // XCD band partition (R5): xcd = b%8 owns pixel band for all depth chunks
    const int b    = blockIdx.x;
    const int xcd  = b % NXCD;
    const int j    = b / NXCD;
    const int wloc = j * WPB + (threadIdx.x >> 2);
    const int l    = threadIdx.x & 3;              // channel octet: groups 2l, 2l+1
    const int ploc = wloc % BAND;
    const int dc   = wloc / BAND;
    const int p    = xcd * BAND + ploc;

    const float fx = (float)(p % W);
    const float fy = (float)(p / W);

    // compiler-visible loads: refq + deps. Loaded FIRST, then pinned complete
    // (dummy-use asm) so the compiler's waitcnt model is empty afterwards.
    h2 refq[4];
    {
        const h2* rp = (const h2*)(feaH + (size_t)p*C + l*8);
        refq[0] = rp[0]; refq[1] = rp[1]; refq[2] = rp[2]; refq[3] = rp[3];
    }
    float deps[DCHUNK];
    #pragma unroll
    for (int dd = 0; dd < DCHUNK; ++dd)
        deps[dd] = depth[(dc*DCHUNK + dd)*HW + p];

    // force refq/deps loads complete here (before any asm load is issued)
    asm volatile("" :: "v"(refq[0]), "v"(refq[1]), "v"(refq[2]), "v"(refq[3]),
                       "v"(deps[0]), "v"(deps[1]), "v"(deps[2]), "v"(deps[3]));

    float rx[3], ry[3], rz[3], tx[3], ty[3], tz[3];
    #pragma unroll
    for (int v = 0; v < 3; ++v) {
        const float* rt = s_rt + v*12;
        rx[v] = fmaf(rt[0], fx, fmaf(rt[1], fy, rt[2]));
        ry[v] = fmaf(rt[3], fx, fmaf(rt[4], fy, rt[5]));
        rz[v] = fmaf(rt[6], fx, fmaf(rt[7], fy, rt[8]));
        tx[v] = rt[9]; ty[v] = rt[10]; tz[v] = rt[11];
    }

    float4 ftaps[2][3][4];
    h2     wgt[2][3][4];
    const float scale = 1.f / 12.f;

    PREP(0, 0)
    PREP(1, 1)
    WAITCNT(12)      // PREP0 landed
    CONS(0, 0)
    PREP(2, 0)
    WAITCNT(14)      // newest 14 = 2 stores + PREP2; PREP1 landed
    CONS(1, 1)
    PREP(3, 1)
    WAITCNT(14)      // newest 14 = 2 stores + PREP3; PREP2 landed
    CONS(2, 0)
    WAITCNT(2)       // newest 2 = CONS2 stores; PREP3 landed
    CONS(3, 1)
}

// ---------- fallback if ws too small (fp32 direct CHW) ----------
__global__ __launch_bounds__(256) void gwc_fallback(
    const float* __restrict__ fea,
    const float* __restrict__ proj,
    const float* __restrict__ depth,
    float* __restrict__ out)
{
    __shared__ float s_rt[(NVIEW-1)*12];
    if (threadIdx.x == 0) compute_rt(proj, s_rt);
    __syncthreads();

    const int tid = blockIdx.x * blockDim.x + threadIdx.x;
    const int p   = tid % HW;
    const float dep = depth[tid];
    const float fx = (float)(p % W);
    const float fy = (float)(p / W);

    float refv[C];
    #pragma unroll
    for (int c = 0; c < C; ++c) refv[c] = fea[c*HW + p];

    float acc[8];
    #pragma unroll
    for (int g = 0; g < 8; ++g) acc[g] = 0.f;

    #pragma unroll
    for (int v = 1; v < NVIEW; ++v) {
        const float* rt = s_rt + (v-1)*12;
        const float X = fmaf(fmaf(rt[0], fx, fmaf(rt[1], fy, rt[2])), dep, rt[9]);
        const float Y = fmaf(fmaf(rt[3], fx, fmaf(rt[4], fy, rt[5])), dep, rt[10]);
        const float Z = fmaf(fmaf(rt[6], fx, fmaf(rt[7], fy, rt[8])), dep, rt[11]);
        const float px = X / Z, py = Y / Z;
        const float x0f = floorf(px), y0f = floorf(py);
        const float dx = px - x0f, dy = py - y0f;
        const int x0 = (int)x0f, y0 = (int)y0f;
        const int x1 = x0 + 1,  y1 = y0 + 1;
        float w00 = (1.f-dx)*(1.f-dy), w10 = dx*(1.f-dy), w01 = (1.f-dx)*dy, w11 = dx*dy;
        const bool vx0 = (x0 >= 0) & (x0 < W), vx1 = (x1 >= 0) & (x1 < W);
        const bool vy0 = (y0 >= 0) & (y0 < H), vy1 = (y1 >= 0) & (y1 < H);
        if (!(vx0 && vy0)) w00 = 0.f;
        if (!(vx1 && vy0)) w10 = 0.f;
        if (!(vx0 && vy1)) w01 = 0.f;
        if (!(vx1 && vy1)) w11 = 0.f;
        const int xc0 = min(max(x0, 0), W-1), xc1 = min(max(x1, 0), W-1);
        const int yc0 = min(max(y0, 0), H-1), yc1 = min(max(y1, 0), H-1);
        const int o00 = yc0*W + xc0, o10 = yc0*W + xc1;
        const int o01 = yc1*W + xc0, o11 = yc1*W + xc1;
        const float* Fv = fea + v*(C*HW);
        #pragma unroll
        for (int c = 0; c < C; ++c) {
            const float* Fc = Fv + c*HW;
            const float s = w00*Fc[o00] + w10*Fc[o10] + w01*Fc[o01] + w11*Fc[o11];
            acc[c >> 2] = fmaf(s, refv[c], acc[c >> 2]);
        }
    }
    const float scale = 1.f / 12.f;
    #pragma unroll
    for (int g = 0; g < 8; ++g)
        out[g*TOTAL + tid] = acc[g] * scale;
}

extern "C" void kernel_launch(void* const* d_in, const int* in_sizes, int n_in,
                              void* d_out, int out_size, void* d_ws, size_t ws_size,
                              hipStream_t stream) {
    const float* fea   = (const float*)d_in[0];
    const float* proj  = (const float*)d_in[1];
    const float* depth = (const float*)d_in[2];
    float* out = (float*)d_out;

    const size_t need = (size_t)NVIEW * HW * C * sizeof(_Float16);  // 4.13 MB
    if (ws_size >= need) {
        _Float16* feaH = (_Float16*)d_ws;
        transpose_h<<<(NVIEW*HW)/256, 256, 0, stream>>>(fea, feaH);
        gwc_main<<<NXCD * BLK_PER_XCD, 256, 0, stream>>>(feaH, proj, depth, out);
    } else {
        gwc_fallback<<<TOTAL/256, 256, 0, stream>>>(fea, proj, depth, out);
    }
}

// Round 7
// 48.271 us; speedup vs baseline: 1.0625x; 1.0625x over previous
//
#include <hip/hip_runtime.h>

// GroupWiseAgg: MVS group-wise correlation cost volume.
// features: (NVIEW=4, C=32, H=112, W=144) fp32
// proj:     (NVIEW, 2, 4, 4) fp32  [0]=extrinsic E, [1]=intrinsic K
// depth:    (D=48, H=112, W=144) fp32
// out:      (G=8, D, H, W) fp32
//
// R7: 4-kernel split.
//   rt_kernel:     fold + fp64 inverse -> rt[36] (once)
//   transpose_h:   features CHW fp32 -> HWC fp16 (64B/pixel)
//   coords_kernel: per (view,d,p): {i16 x0, i16 y0, 4xfp16 weights} packed
//                  12B, XCD-banded to match the consumer
//   gwc_main:      per (d,p) cluster of 4 lanes: preload 12 coord records,
//                  then per depth: unpack -> 12 tap gathers -> packed blend.
// Removes the 4x-redundant per-lane coord math and the serial VALU prefix
// in front of every gather batch.

typedef _Float16 h2  __attribute__((ext_vector_type(2)));
typedef _Float16 h8v __attribute__((ext_vector_type(8)));

constexpr int NVIEW = 4;
constexpr int C     = 32;
constexpr int D     = 48;
constexpr int H     = 112;
constexpr int W     = 144;
constexpr int HW    = H * W;        // 16128
constexpr int TOTAL = D * HW;       // 774144
constexpr int DCHUNK = 4;
constexpr int NDC    = D / DCHUNK;  // 12
constexpr int NXCD   = 8;
constexpr int BAND   = HW / NXCD;   // 2016 pixels
constexpr int WPB    = 64;          // wids per block
constexpr int BLK_PER_XCD = (BAND * NDC) / WPB;   // 378
constexpr int MAIN_BLOCKS = NXCD * BLK_PER_XCD;   // 3024

// ws layout
constexpr size_t FEAH_BYTES = (size_t)NVIEW * HW * C * 2;   // 4,128,768
constexpr size_t RT_OFF     = FEAH_BYTES;                   // 36 floats
constexpr size_t CA_OFF     = RT_OFF + 256;                 // 8-aligned
constexpr size_t CA_BYTES   = (size_t)3 * TOTAL * 8;        // xy + wA
constexpr size_t CB_OFF     = CA_OFF + CA_BYTES;
constexpr size_t CB_BYTES   = (size_t)3 * TOTAL * 4;        // wB
constexpr size_t WS_NEED    = CB_OFF + CB_BYTES;            // ~32 MB

#if __has_builtin(__builtin_amdgcn_fdot2)
__device__ inline float dot2f(h2 a, h2 b, float c) {
    return __builtin_amdgcn_fdot2(a, b, c, false);
}
#else
__device__ inline float dot2f(h2 a, h2 b, float c) {
    return fmaf((float)a.x, (float)b.x, fmaf((float)a.y, (float)b.y, c));
}
#endif

__device__ inline h2 as_h2(float f) { union { float f; h2 h; } u; u.f = f; return u.h; }
__device__ inline h2 u2h(uint v)    { union { uint u; h2 h; } x; x.u = v; return x.h; }
__device__ inline uint h2u(h2 v)    { union { uint u; h2 h; } x; x.h = v; return x.u; }

// ---------- matrix helpers ----------
__device__ inline void fold_mat(const float* pm, double out[16]) {
    const float* E = pm;
    const float* K = pm + 16;
    for (int i = 0; i < 3; ++i)
        for (int j = 0; j < 4; ++j) {
            double s = 0.0;
            for (int k = 0; k < 3; ++k) s += (double)K[i*4+k] * (double)E[k*4+j];
            out[i*4+j] = s;
        }
    for (int j = 0; j < 4; ++j) out[12+j] = (double)E[12+j];
}

__device__ inline void inv4(const double A[16], double out[16]) {
    double M[4][8];
    for (int r = 0; r < 4; ++r) {
        for (int c = 0; c < 4; ++c) M[r][c] = A[r*4+c];
        for (int c = 0; c < 4; ++c) M[r][4+c] = (r == c) ? 1.0 : 0.0;
    }
    for (int col = 0; col < 4; ++col) {
        int piv = col;
        double best = fabs(M[col][col]);
        for (int r = col+1; r < 4; ++r) {
            double v = fabs(M[r][col]);
            if (v > best) { best = v; piv = r; }
        }
        if (piv != col)
            for (int c = 0; c < 8; ++c) { double t = M[col][c]; M[col][c] = M[piv][c]; M[piv][c] = t; }
        double ip = 1.0 / M[col][col];
        for (int c = 0; c < 8; ++c) M[col][c] *= ip;
        for (int r = 0; r < 4; ++r) {
            if (r == col) continue;
            double f = M[r][col];
            if (f != 0.0)
                for (int c = 0; c < 8; ++c) M[r][c] -= f * M[col][c];
        }
    }
    for (int r = 0; r < 4; ++r)
        for (int c = 0; c < 4; ++c) out[r*4+c] = M[r][4+c];
}

__device__ inline void compute_rt(const float* proj, float* dst) {
    double Pref[16], Pinv[16];
    fold_mat(proj, Pref);
    inv4(Pref, Pinv);
    for (int v = 1; v < NVIEW; ++v) {
        double Ps[16], Pr[16];
        fold_mat(proj + v*32, Ps);
        for (int i = 0; i < 4; ++i)
            for (int j = 0; j < 4; ++j) {
                double s = 0.0;
                for (int k = 0; k < 4; ++k) s += Ps[i*4+k] * Pinv[k*4+j];
                Pr[i*4+j] = s;
            }
        float* o = dst + (v-1)*12;
        for (int i = 0; i < 3; ++i)
            for (int j = 0; j < 3; ++j) o[i*3+j] = (float)Pr[i*4+j];
        for (int i = 0; i < 3; ++i) o[9+i] = (float)Pr[i*4+3];
    }
}

// ---------- kernel 0: rt once ----------
__global__ void rt_kernel(const float* __restrict__ proj, float* __restrict__ rtbuf) {
    if (threadIdx.x == 0) compute_rt(proj, rtbuf);
}

// ---------- kernel 1: transpose CHW fp32 -> HWC fp16 ----------
__global__ __launch_bounds__(256) void transpose_h(
    const float* __restrict__ fea, _Float16* __restrict__ feaH)
{
    const int t = blockIdx.x * blockDim.x + threadIdx.x;  // v*HW + p
    const int v = t / HW;
    const int p = t - v * HW;
    const float* src = fea + (size_t)v*C*HW + p;
    h8v ov[4];
    #pragma unroll
    for (int q = 0; q < 4; ++q) {
        #pragma unroll
        for (int k = 0; k < 8; ++k) ov[q][k] = (_Float16)src[(q*8+k)*HW];
    }
    h8v* dst = (h8v*)(feaH + (size_t)t * C);
    #pragma unroll
    for (int q = 0; q < 4; ++q) dst[q] = ov[q];
}

// ---------- kernel 2: warp coords, banded like the consumer ----------
__global__ __launch_bounds__(256) void coords_kernel(
    const float* __restrict__ depth,   // (D, HW)
    const float* __restrict__ rtbuf,   // 36 floats
    uint2* __restrict__ planeA,        // (3, TOTAL): {packed x0y0, packed w00w10}
    uint*  __restrict__ planeB)        // (3, TOTAL): packed w01w11
{
    const int b  = blockIdx.x;         // 0 .. 3*3024-1
    const int v  = b / MAIN_BLOCKS;    // 0..2 (uniform per block)
    const int b2 = b - v * MAIN_BLOCKS;
    const int xcd = b2 % NXCD;
    const int j   = b2 / NXCD;
    const int local = j * 256 + threadIdx.x;   // 0 .. BAND*D-1
    const int ploc  = local % BAND;
    const int d     = local / BAND;
    const int p     = xcd * BAND + ploc;
    const int pd    = d * HW + p;

    const float* rt = rtbuf + v*12;
    const float fx = (float)(p % W);
    const float fy = (float)(p / W);
    const float dep = depth[pd];

    const float X = fmaf(fmaf(rt[0], fx, fmaf(rt[1], fy, rt[2])), dep, rt[9]);
    const float Y = fmaf(fmaf(rt[3], fx, fmaf(rt[4], fy, rt[5])), dep, rt[10]);
    const float Z = fmaf(fmaf(rt[6], fx, fmaf(rt[7], fy, rt[8])), dep, rt[11]);
    const float iZ = __builtin_amdgcn_rcpf(Z);
    const float px = X * iZ;
    const float py = Y * iZ;

    const float x0f = floorf(px), y0f = floorf(py);
    const float dx = px - x0f, dy = py - y0f;
    const int x0 = (int)x0f, y0 = (int)y0f;
    const int x1 = x0 + 1,  y1 = y0 + 1;

    float w00 = (1.f-dx)*(1.f-dy);
    float w10 = dx*(1.f-dy);
    float w01 = (1.f-dx)*dy;
    float w11 = dx*dy;

    const bool vx0 = (x0 >= 0) & (x0 < W);
    const bool vx1 = (x1 >= 0) & (x1 < W);
    const bool vy0 = (y0 >= 0) & (y0 < H);
    const bool vy1 = (y1 >= 0) & (y1 < H);
    if (!(vx0 && vy0)) w00 = 0.f;
    if (!(vx1 && vy0)) w10 = 0.f;
    if (!(vx0 && vy1)) w01 = 0.f;
    if (!(vx1 && vy1)) w11 = 0.f;

    const int x0s = min(max(x0, -32768), 32767);
    const int y0s = min(max(y0, -32768), 32767);
    const uint xy = (uint)(x0s & 0xffff) | ((uint)(y0s & 0xffff) << 16);

    h2 wa; wa.x = (_Float16)w00; wa.y = (_Float16)w10;
    h2 wb; wb.x = (_Float16)w01; wb.y = (_Float16)w11;

    const size_t idx = (size_t)v * TOTAL + pd;
    planeA[idx] = make_uint2(xy, h2u(wa));
    planeB[idx] = h2u(wb);
}

// ---------- kernel 3: main gather+blend ----------
__global__ __launch_bounds__(256) void gwc_main(
    const _Float16* __restrict__ feaH,   // (NVIEW, HW, C) fp16
    const uint2* __restrict__ planeA,
    const uint*  __restrict__ planeB,
    float* __restrict__ out)             // (G=8, D, HW)
{
    const int b    = blockIdx.x;
    const int xcd  = b % NXCD;
    const int j    = b / NXCD;
    const int wloc = j * WPB + (threadIdx.x >> 2);
    const int l    = threadIdx.x & 3;              // channel octet: groups 2l, 2l+1
    const int ploc = wloc % BAND;
    const int dc   = wloc / BAND;
    const int p    = xcd * BAND + ploc;
    const int pd0  = dc * DCHUNK * HW + p;

    // ref features: 16B (8 channels) for this lane
    h2 refq[4];
    {
        const h2* rp = (const h2*)(feaH + (size_t)p*C + l*8);
        refq[0] = rp[0]; refq[1] = rp[1]; refq[2] = rp[2]; refq[3] = rp[3];
    }

    // preload all 12 coord records (4 depths x 3 views)
    uint2 ca[DCHUNK][3];
    uint  cb[DCHUNK][3];
    #pragma unroll
    for (int dd = 0; dd < DCHUNK; ++dd) {
        const int pdi = pd0 + dd*HW;
        #pragma unroll
        for (int v = 0; v < 3; ++v) {
            const size_t idx = (size_t)v * TOTAL + pdi;
            ca[dd][v] = planeA[idx];
            cb[dd][v] = planeB[idx];
        }
    }

    const float scale = 1.f / 12.f;

    #pragma unroll
    for (int dd = 0; dd < DCHUNK; ++dd) {
        float accA = 0.f, accB = 0.f;
        #pragma unroll
        for (int v = 0; v < 3; ++v) {
            const uint xy = ca[dd][v].x;
            const h2 wa = u2h(ca[dd][v].y);
            const h2 wb = u2h(cb[dd][v]);

            const int x0 = (int)(short)(xy & 0xffffu);
            const int y0 = ((int)xy) >> 16;
            const int xc0 = min(max(x0, 0), W-1), xc1 = min(max(x0+1, 0), W-1);
            const int yc0 = min(max(y0, 0), H-1), yc1 = min(max(y0+1, 0), H-1);
            const int r0 = yc0 * W, r1 = yc1 * W;

            const _Float16* bv = feaH + (size_t)(v+1)*HW*C + l*8;
            const float4 t00 = *(const float4*)(bv + (size_t)(r0+xc0)*C);
            const float4 t10 = *(const float4*)(bv + (size_t)(r0+xc1)*C);
            const float4 t01 = *(const float4*)(bv + (size_t)(r1+xc0)*C);
            const float4 t11 = *(const float4*)(bv + (size_t)(r1+xc1)*C);

            h2 w00s; w00s.x = wa.x; w00s.y = wa.x;
            h2 w10s; w10s.x = wa.y; w10s.y = wa.y;
            h2 w01s; w01s.x = wb.x; w01s.y = wb.x;
            h2 w11s; w11s.x = wb.y; w11s.y = wb.y;

            h2 s0 = w00s*as_h2(t00.x) + w10s*as_h2(t10.x) + w01s*as_h2(t01.x) + w11s*as_h2(t11.x);
            h2 s1 = w00s*as_h2(t00.y) + w10s*as_h2(t10.y) + w01s*as_h2(t01.y) + w11s*as_h2(t11.y);
            h2 s2 = w00s*as_h2(t00.z) + w10s*as_h2(t10.z) + w01s*as_h2(t01.z) + w11s*as_h2(t11.z);
            h2 s3 = w00s*as_h2(t00.w) + w10s*as_h2(t10.w) + w01s*as_h2(t01.w) + w11s*as_h2(t11.w);

            accA = dot2f(s0, refq[0], accA);
            accA = dot2f(s1, refq[1], accA);
            accB = dot2f(s2, refq[2], accB);
            accB = dot2f(s3, refq[3], accB);
        }
        const int pdi = pd0 + dd*HW;
        __builtin_nontemporal_store(accA * scale, &out[(2*l  )*TOTAL + pdi]);
        __builtin_nontemporal_store(accB * scale, &out[(2*l+1)*TOTAL + pdi]);
    }
}

// ---------- mid tier: fp16 + banding, coords computed in-kernel (R5-like) ----------
__global__ __launch_bounds__(256) void gwc_mid(
    const _Float16* __restrict__ feaH,
    const float* __restrict__ proj,
    const float* __restrict__ depth,
    float* __restrict__ out)
{
    __shared__ float s_rt[(NVIEW-1)*12];
    if (threadIdx.x == 0) compute_rt(proj, s_rt);
    __syncthreads();

    const int b    = blockIdx.x;
    const int xcd  = b % NXCD;
    const int j    = b / NXCD;
    const int wloc = j * WPB + (threadIdx.x >> 2);
    const int l    = threadIdx.x & 3;
    const int ploc = wloc % BAND;
    const int dc   = wloc / BAND;
    const int p    = xcd * BAND + ploc;

    const float fx = (float)(p % W);
    const float fy = (float)(p / W);

    h2 refq[4];
    {
        const h2* rp = (const h2*)(feaH + (size_t)p*C + l*8);
        refq[0] = rp[0]; refq[1] = rp[1]; refq[2] = rp[2]; refq[3] = rp[3];
    }

    float rx[3], ry[3], rz[3], tx[3], ty[3], tz[3];
    #pragma unroll
    for (int v = 0; v < 3; ++v) {
        const float* rt = s_rt + v*12;
        rx[v] = fmaf(rt[0], fx, fmaf(rt[1], fy, rt[2]));
        ry[v] = fmaf(rt[3], fx, fmaf(rt[4], fy, rt[5]));
        rz[v] = fmaf(rt[6], fx, fmaf(rt[7], fy, rt[8]));
        tx[v] = rt[9]; ty[v] = rt[10]; tz[v] = rt[11];
    }

    const float scale = 1.f / 12.f;
    for (int dd = 0; dd < DCHUNK; ++dd) {
        const int didx = (dc*DCHUNK + dd)*HW + p;
        const float dep = depth[didx];
        float accA = 0.f, accB = 0.f;
        #pragma unroll
        for (int v = 0; v < 3; ++v) {
            const float X = fmaf(rx[v], dep, tx[v]);
            const float Y = fmaf(ry[v], dep, ty[v]);
            const float Z = fmaf(rz[v], dep, tz[v]);
            const float iZ = __builtin_amdgcn_rcpf(Z);
            const float px = X * iZ, py = Y * iZ;
            const float x0f = floorf(px), y0f = floorf(py);
            const float dx = px - x0f, dy = py - y0f;
            const int x0 = (int)x0f, y0 = (int)y0f;
            const int x1 = x0 + 1,  y1 = y0 + 1;
            float w00 = (1.f-dx)*(1.f-dy), w10 = dx*(1.f-dy);
            float w01 = (1.f-dx)*dy,       w11 = dx*dy;
            const bool vx0 = (x0 >= 0) & (x0 < W), vx1 = (x1 >= 0) & (x1 < W);
            const bool vy0 = (y0 >= 0) & (y0 < H), vy1 = (y1 >= 0) & (y1 < H);
            if (!(vx0 && vy0)) w00 = 0.f;
            if (!(vx1 && vy0)) w10 = 0.f;
            if (!(vx0 && vy1)) w01 = 0.f;
            if (!(vx1 && vy1)) w11 = 0.f;
            const int xc0 = min(max(x0,0),W-1), xc1 = min(max(x1,0),W-1);
            const int yc0 = min(max(y0,0),H-1), yc1 = min(max(y1,0),H-1);
            const int r0 = yc0*W, r1 = yc1*W;
            const _Float16* bv = feaH + (size_t)(v+1)*HW*C + l*8;
            const float4 t00 = *(const float4*)(bv + (size_t)(r0+xc0)*C);
            const float4 t10 = *(const float4*)(bv + (size_t)(r0+xc1)*C);
            const float4 t01 = *(const float4*)(bv + (size_t)(r1+xc0)*C);
            const float4 t11 = *(const float4*)(bv + (size_t)(r1+xc1)*C);
            h2 w00s; w00s.x=(_Float16)w00; w00s.y=w00s.x;
            h2 w10s; w10s.x=(_Float16)w10; w10s.y=w10s.x;
            h2 w01s; w01s.x=(_Float16)w01; w01s.y=w01s.x;
            h2 w11s; w11s.x=(_Float16)w11; w11s.y=w11s.x;
            h2 s0 = w00s*as_h2(t00.x) + w10s*as_h2(t10.x) + w01s*as_h2(t01.x) + w11s*as_h2(t11.x);
            h2 s1 = w00s*as_h2(t00.y) + w10s*as_h2(t10.y) + w01s*as_h2(t01.y) + w11s*as_h2(t11.y);
            h2 s2 = w00s*as_h2(t00.z) + w10s*as_h2(t10.z) + w01s*as_h2(t01.z) + w11s*as_h2(t11.z);
            h2 s3 = w00s*as_h2(t00.w) + w10s*as_h2(t10.w) + w01s*as_h2(t01.w) + w11s*as_h2(t11.w);
            accA = dot2f(s0, refq[0], accA);
            accA = dot2f(s1, refq[1], accA);
            accB = dot2f(s2, refq[2], accB);
            accB = dot2f(s3, refq[3], accB);
        }
        __builtin_nontemporal_store(accA * scale, &out[(2*l  )*TOTAL + didx]);
        __builtin_nontemporal_store(accB * scale, &out[(2*l+1)*TOTAL + didx]);
    }
}

// ---------- last-resort fallback (R1 monolithic fp32) ----------
__global__ __launch_bounds__(256) void gwc_fallback(
    const float* __restrict__ fea,
    const float* __restrict__ proj,
    const float* __restrict__ depth,
    float* __restrict__ out)
{
    __shared__ float s_rt[(NVIEW-1)*12];
    if (threadIdx.x == 0) compute_rt(proj, s_rt);
    __syncthreads();

    const int tid = blockIdx.x * blockDim.x + threadIdx.x;
    const int p   = tid % HW;
    const float dep = depth[tid];
    const float fx = (float)(p % W);
    const float fy = (float)(p / W);

    float refv[C];
    #pragma unroll
    for (int c = 0; c < C; ++c) refv[c] = fea[c*HW + p];

    float acc[8];
    #pragma unroll
    for (int g = 0; g < 8; ++g) acc[g] = 0.f;

    #pragma unroll
    for (int v = 1; v < NVIEW; ++v) {
        const float* rt = s_rt + (v-1)*12;
        const float X = fmaf(fmaf(rt[0], fx, fmaf(rt[1], fy, rt[2])), dep, rt[9]);
        const float Y = fmaf(fmaf(rt[3], fx, fmaf(rt[4], fy, rt[5])), dep, rt[10]);
        const float Z = fmaf(fmaf(rt[6], fx, fmaf(rt[7], fy, rt[8])), dep, rt[11]);
        const float px = X / Z, py = Y / Z;
        const float x0f = floorf(px), y0f = floorf(py);
        const float dx = px - x0f, dy = py - y0f;
        const int x0 = (int)x0f, y0 = (int)y0f;
        const int x1 = x0 + 1,  y1 = y0 + 1;
        float w00 = (1.f-dx)*(1.f-dy), w10 = dx*(1.f-dy), w01 = (1.f-dx)*dy, w11 = dx*dy;
        const bool vx0 = (x0 >= 0) & (x0 < W), vx1 = (x1 >= 0) & (x1 < W);
        const bool vy0 = (y0 >= 0) & (y0 < H), vy1 = (y1 >= 0) & (y1 < H);
        if (!(vx0 && vy0)) w00 = 0.f;
        if (!(vx1 && vy0)) w10 = 0.f;
        if (!(vx0 && vy1)) w01 = 0.f;
        if (!(vx1 && vy1)) w11 = 0.f;
        const int xc0 = min(max(x0, 0), W-1), xc1 = min(max(x1, 0), W-1);
        const int yc0 = min(max(y0, 0), H-1), yc1 = min(max(y1, 0), H-1);
        const int o00 = yc0*W + xc0, o10 = yc0*W + xc1;
        const int o01 = yc1*W + xc0, o11 = yc1*W + xc1;
        const float* Fv = fea + v*(C*HW);
        #pragma unroll
        for (int c = 0; c < C; ++c) {
            const float* Fc = Fv + c*HW;
            const float s = w00*Fc[o00] + w10*Fc[o10] + w01*Fc[o01] + w11*Fc[o11];
            acc[c >> 2] = fmaf(s, refv[c], acc[c >> 2]);
        }
    }
    const float scale = 1.f / 12.f;
    #pragma unroll
    for (int g = 0; g < 8; ++g)
        out[g*TOTAL + tid] = acc[g] * scale;
}

extern "C" void kernel_launch(void* const* d_in, const int* in_sizes, int n_in,
                              void* d_out, int out_size, void* d_ws, size_t ws_size,
                              hipStream_t stream) {
    const float* fea   = (const float*)d_in[0];
    const float* proj  = (const float*)d_in[1];
    const float* depth = (const float*)d_in[2];
    float* out = (float*)d_out;
    char* ws = (char*)d_ws;

    if (ws_size >= WS_NEED) {
        _Float16* feaH = (_Float16*)(ws);
        float*    rtb  = (float*)(ws + RT_OFF);
        uint2*    pA   = (uint2*)(ws + CA_OFF);
        uint*     pB   = (uint*)(ws + CB_OFF);
        rt_kernel<<<1, 64, 0, stream>>>(proj, rtb);
        transpose_h<<<(NVIEW*HW)/256, 256, 0, stream>>>(fea, feaH);
        coords_kernel<<<3*MAIN_BLOCKS, 256, 0, stream>>>(depth, rtb, pA, pB);
        gwc_main<<<MAIN_BLOCKS, 256, 0, stream>>>(feaH, pA, pB, out);
    } else if (ws_size >= FEAH_BYTES) {
        _Float16* feaH = (_Float16*)ws;
        transpose_h<<<(NVIEW*HW)/256, 256, 0, stream>>>(fea, feaH);
        gwc_mid<<<MAIN_BLOCKS, 256, 0, stream>>>(feaH, proj, depth, out);
    } else {
        gwc_fallback<<<TOTAL/256, 256, 0, stream>>>(fea, proj, depth, out);
    }
}